// Round 18
// baseline (128.429 us; speedup 1.0000x reference)
//
#include <hip/hip_runtime.h>
#include <math.h>

#define NTGT 40000
#define NSRC 40000
#define NEDGE 640000
#define LOG2E 1.44269504088896f
#define KGROW 256  // shorts per KG row: 256 K/GV interleaved = 512B, 8 aligned lines
#define CAP 64     // max edges per target (Poisson(16), max~34; P(>63)~1e-17)

typedef __attribute__((ext_vector_type(8))) short bfrag;   // 8 bf16 (4 VGPRs)
typedef __attribute__((ext_vector_type(4))) short bhalf4;  // 8B
typedef __attribute__((ext_vector_type(8))) short bhalf8;  // 16B
typedef __attribute__((ext_vector_type(4))) float f4acc;   // MFMA accumulator

__device__ __forceinline__ ushort f2bf(float f) {
  uint u = __float_as_uint(f);
  u += 0x7fffu + ((u >> 16) & 1u);  // RNE
  return (ushort)(u >> 16);
}
__device__ __forceinline__ float bflo(uint u) { return __uint_as_float(u << 16); }
__device__ __forceinline__ float bfhi(uint u) { return __uint_as_float(u & 0xffff0000u); }
__device__ __forceinline__ float bf2f(short s) { return __uint_as_float(((uint)(ushort)s) << 16); }
__device__ __forceinline__ float sigmoidf_fast(float x) { return 1.0f / (1.0f + __expf(-x)); }

// ---------------- prep: weight transpose/convert + counter zeroing ----------------
// blocks 0..5: square mats; 6: Wbs bias mat; 7..631: zero cntp (625*1024 ints)
__global__ __launch_bounds__(256) void k_prep(const float* __restrict__ Wq,
                                              const float* __restrict__ Wkv,
                                              const float* __restrict__ Wgt_w,
                                              const float* __restrict__ Wgs_w,
                                              const float* __restrict__ Wo,
                                              const float* __restrict__ Wbs,
                                              int* __restrict__ cntp,
                                              short* __restrict__ WqT, short* __restrict__ WkT,
                                              short* __restrict__ WvT, short* __restrict__ WgtT,
                                              short* __restrict__ WgsT, short* __restrict__ WoT,
                                              short* __restrict__ WbsT) {
  const int b = blockIdx.x;
  const int tid = threadIdx.x;
  if (b >= 7) {
    int i = (b - 7) * 1024 + tid * 4;  // 625*1024 = 640000 = 40000*16 exact
    int4 z = {0, 0, 0, 0};
    *reinterpret_cast<int4*>(cntp + i) = z;
    return;
  }
  if (b == 6) {
    for (int idx = tid; idx < 16 * 128; idx += 256) {
      int n = idx >> 7, k = idx & 127;
      WbsT[idx] = (n < 8) ? (short)f2bf(Wbs[k * 8 + n]) : (short)0;
    }
    return;
  }
  __shared__ short T[128][136];
  const float* src;
  int ld, off;
  short* dst;
  switch (b) {
    case 0: src = Wq;    ld = 128; off = 0;   dst = WqT;  break;
    case 1: src = Wkv;   ld = 256; off = 0;   dst = WkT;  break;
    case 2: src = Wkv;   ld = 256; off = 128; dst = WvT;  break;
    case 3: src = Wgt_w; ld = 128; off = 0;   dst = WgtT; break;
    case 4: src = Wgs_w; ld = 128; off = 0;   dst = WgsT; break;
    default:src = Wo;    ld = 128; off = 0;   dst = WoT;  break;
  }
  for (int i = tid; i < 128 * 32; i += 256) {
    int k = i >> 5, c4 = (i & 31) * 4;
    float4 v = *reinterpret_cast<const float4*>(src + (size_t)k * ld + off + c4);
    T[c4 + 0][k] = (short)f2bf(v.x);
    T[c4 + 1][k] = (short)f2bf(v.y);
    T[c4 + 2][k] = (short)f2bf(v.z);
    T[c4 + 3][k] = (short)f2bf(v.w);
  }
  __syncthreads();
  for (int u = tid; u < 128 * 16; u += 256) {
    int n = u >> 4, o = (u & 15) * 8;
    *reinterpret_cast<bhalf8*>(dst + (size_t)n * 128 + o) =
        *reinterpret_cast<const bhalf8*>(&T[n][o]);
  }
}

// ---------------- XCD-partitioned bucket fill ----------------
__global__ __launch_bounds__(512) void k_fill(const int* __restrict__ inc_tgt,
                                              const int* __restrict__ inc_src,
                                              int* __restrict__ cntp,
                                              ushort* __restrict__ elist) {
  const int tid = threadIdx.x;
  const int part = blockIdx.x & 7;
  const int ebase = (blockIdx.x >> 3) * 2000;  // 320 chunks * 2000 = 640000 exact
#pragma unroll
  for (int k = 0; k < 4; ++k) {
    int off = k * 512 + tid;
    if (off < 2000) {
      int e = ebase + off;
      int t = inc_tgt[e];
      if ((t & 7) == part) {
        int pos = atomicAdd(&cntp[t << 4], 1);
        pos = min(pos, CAP - 1);  // never triggers; guards OOB
        elist[t * CAP + pos] = (ushort)inc_src[e];
      }
    }
  }
}

#define MFMA16(a, b, c) __builtin_amdgcn_mfma_f32_16x16x32_bf16(a, b, c, 0, 0, 0)

// ---------------- projections: double-buffered, ONE barrier per tile ----------------
__device__ __forceinline__ void stage_issue(const float* __restrict__ X, size_t row0,
                                            float4 ld[4], int tid) {
#pragma unroll
  for (int it = 0; it < 4; ++it) {
    int i = it * 512 + tid;
    int r = i >> 5, c4 = (i & 31) * 4;
    ld[it] = *reinterpret_cast<const float4*>(X + (row0 + r) * 128 + c4);
  }
}
__device__ __forceinline__ void stage_write(short (*Xs)[136], const float4 ld[4], int tid) {
#pragma unroll
  for (int it = 0; it < 4; ++it) {
    int i = it * 512 + tid;
    int r = i >> 5, c4 = (i & 31) * 4;
    bhalf4 o;
    o[0] = (short)f2bf(ld[it].x); o[1] = (short)f2bf(ld[it].y);
    o[2] = (short)f2bf(ld[it].z); o[3] = (short)f2bf(ld[it].w);
    *reinterpret_cast<bhalf4*>(&Xs[r][c4]) = o;
  }
}

__global__ __launch_bounds__(512) void k_proj(const float* __restrict__ Xt,
                                              const float* __restrict__ Xsrc,
                                              const short* __restrict__ WqT,
                                              const short* __restrict__ WgtT,
                                              const short* __restrict__ WkT,
                                              const short* __restrict__ WvT,
                                              const short* __restrict__ WgsT,
                                              const short* __restrict__ WbsT,
                                              const float* __restrict__ Wgt_b,
                                              const float* __restrict__ Wgs_b,
                                              short* __restrict__ Qb, short* __restrict__ gtb,
                                              short* __restrict__ KG,
                                              short* __restrict__ bsb) {
  const int tid = threadIdx.x;
  __shared__ short Xs[2][64][136];   // 34.8 KB
  __shared__ short Stg[2][64][256];  // 64 KB  (98.8 KB total -> 1 block/CU)
  const int w = tid >> 6, lane = tid & 63;
  const int nl = lane & 15;
  const int kg = (lane >> 4) * 8;
  const int r4 = (lane >> 4) * 4;
  const int c0 = w * 16;
  const bool is_src = blockIdx.x >= 125;
  const int t0 = (is_src ? blockIdx.x - 125 : blockIdx.x) * 5;
  const float* X = is_src ? Xsrc : Xt;

  if (!is_src) {
    bfrag Bq[4], Bg[4];
#pragma unroll
    for (int ks = 0; ks < 4; ++ks) {
      const size_t wo = (size_t)(c0 + nl) * 128 + ks * 32 + kg;
      Bq[ks] = *reinterpret_cast<const bfrag*>(WqT + wo);
      Bg[ks] = *reinterpret_cast<const bfrag*>(WgtT + wo);
    }
    const int c = c0 + nl;
    const float gb = Wgt_b[c];
    {
      float4 ld[4];
      stage_issue(X, (size_t)t0 * 64, ld, tid);
      stage_write(Xs[0], ld, tid);
    }
    __syncthreads();
    int cur = 0;
    for (int ti = 0; ti < 5; ++ti) {
      const size_t row0 = (size_t)(t0 + ti) * 64;
      float4 ld[4];
      if (ti < 4) stage_issue(X, row0 + 64, ld, tid);
      f4acc aQ[4] = {}, aG[4] = {};
#pragma unroll
      for (int ks = 0; ks < 4; ++ks) {
        const int ko = ks * 32 + kg;
        bfrag a0 = *reinterpret_cast<const bfrag*>(&Xs[cur][nl][ko]);
        bfrag a1 = *reinterpret_cast<const bfrag*>(&Xs[cur][16 + nl][ko]);
        bfrag a2 = *reinterpret_cast<const bfrag*>(&Xs[cur][32 + nl][ko]);
        bfrag a3 = *reinterpret_cast<const bfrag*>(&Xs[cur][48 + nl][ko]);
        aQ[0] = MFMA16(a0, Bq[ks], aQ[0]);
        aQ[1] = MFMA16(a1, Bq[ks], aQ[1]);
        aQ[2] = MFMA16(a2, Bq[ks], aQ[2]);
        aQ[3] = MFMA16(a3, Bq[ks], aQ[3]);
        aG[0] = MFMA16(a0, Bg[ks], aG[0]);
        aG[1] = MFMA16(a1, Bg[ks], aG[1]);
        aG[2] = MFMA16(a2, Bg[ks], aG[2]);
        aG[3] = MFMA16(a3, Bg[ks], aG[3]);
      }
#pragma unroll
      for (int rf = 0; rf < 4; ++rf)
#pragma unroll
        for (int j = 0; j < 4; ++j) {
          int r = rf * 16 + r4 + j;
          Stg[cur][r][c] = (short)f2bf(aQ[rf][j] * (0.25f * LOG2E));
          Stg[cur][r][128 + c] = (short)f2bf(sigmoidf_fast(aG[rf][j] + gb));
        }
      if (ti > 0) {  // flush previous tile (other Stg buffer) — overlaps this tile
        const size_t rp = (size_t)(t0 + ti - 1) * 64;
        for (int u = tid; u < 1024; u += 512) {
          int r = u >> 4, o = (u & 15) * 8;
          *reinterpret_cast<bhalf8*>(Qb + (rp + r) * 128 + o) =
              *reinterpret_cast<const bhalf8*>(&Stg[cur ^ 1][r][o]);
          *reinterpret_cast<bhalf8*>(gtb + (rp + r) * 128 + o) =
              *reinterpret_cast<const bhalf8*>(&Stg[cur ^ 1][r][128 + o]);
        }
      }
      if (ti < 4) stage_write(Xs[cur ^ 1], ld, tid);
      __syncthreads();
      cur ^= 1;
    }
    {  // final flush: tile 4 lives in Stg[cur^1]
      const size_t rp = (size_t)(t0 + 4) * 64;
      for (int u = tid; u < 1024; u += 512) {
        int r = u >> 4, o = (u & 15) * 8;
        *reinterpret_cast<bhalf8*>(Qb + (rp + r) * 128 + o) =
            *reinterpret_cast<const bhalf8*>(&Stg[cur ^ 1][r][o]);
        *reinterpret_cast<bhalf8*>(gtb + (rp + r) * 128 + o) =
            *reinterpret_cast<const bhalf8*>(&Stg[cur ^ 1][r][128 + o]);
      }
    }
  } else {
    bfrag Bk[4], Bv[4], Bg[4], Bb[4];
#pragma unroll
    for (int ks = 0; ks < 4; ++ks) {
      const size_t wo = (size_t)(c0 + nl) * 128 + ks * 32 + kg;
      Bk[ks] = *reinterpret_cast<const bfrag*>(WkT + wo);
      Bv[ks] = *reinterpret_cast<const bfrag*>(WvT + wo);
      Bg[ks] = *reinterpret_cast<const bfrag*>(WgsT + wo);
      Bb[ks] = *reinterpret_cast<const bfrag*>(WbsT + (size_t)nl * 128 + ks * 32 + kg);
    }
    const int c = c0 + nl;
    const int slot = (c >> 1) * 4 + (c & 1);
    const float gb = Wgs_b[c];
    {
      float4 ld[4];
      stage_issue(X, (size_t)t0 * 64, ld, tid);
      stage_write(Xs[0], ld, tid);
    }
    __syncthreads();
    int cur = 0;
    for (int ti = 0; ti < 5; ++ti) {
      const size_t row0 = (size_t)(t0 + ti) * 64;
      float4 ld[4];
      if (ti < 4) stage_issue(X, row0 + 64, ld, tid);
      f4acc aK[4] = {}, aV[4] = {}, aG[4] = {}, aB[4] = {};
#pragma unroll
      for (int ks = 0; ks < 4; ++ks) {
        const int ko = ks * 32 + kg;
        bfrag a0 = *reinterpret_cast<const bfrag*>(&Xs[cur][nl][ko]);
        bfrag a1 = *reinterpret_cast<const bfrag*>(&Xs[cur][16 + nl][ko]);
        bfrag a2 = *reinterpret_cast<const bfrag*>(&Xs[cur][32 + nl][ko]);
        bfrag a3 = *reinterpret_cast<const bfrag*>(&Xs[cur][48 + nl][ko]);
        aK[0] = MFMA16(a0, Bk[ks], aK[0]);
        aK[1] = MFMA16(a1, Bk[ks], aK[1]);
        aK[2] = MFMA16(a2, Bk[ks], aK[2]);
        aK[3] = MFMA16(a3, Bk[ks], aK[3]);
        aV[0] = MFMA16(a0, Bv[ks], aV[0]);
        aV[1] = MFMA16(a1, Bv[ks], aV[1]);
        aV[2] = MFMA16(a2, Bv[ks], aV[2]);
        aV[3] = MFMA16(a3, Bv[ks], aV[3]);
        aG[0] = MFMA16(a0, Bg[ks], aG[0]);
        aG[1] = MFMA16(a1, Bg[ks], aG[1]);
        aG[2] = MFMA16(a2, Bg[ks], aG[2]);
        aG[3] = MFMA16(a3, Bg[ks], aG[3]);
        if (w == 0) {
          aB[0] = MFMA16(a0, Bb[ks], aB[0]);
          aB[1] = MFMA16(a1, Bb[ks], aB[1]);
          aB[2] = MFMA16(a2, Bb[ks], aB[2]);
          aB[3] = MFMA16(a3, Bb[ks], aB[3]);
        }
      }
#pragma unroll
      for (int rf = 0; rf < 4; ++rf)
#pragma unroll
        for (int j = 0; j < 4; ++j) {
          int r = rf * 16 + r4 + j;
          float g = sigmoidf_fast(aG[rf][j] + gb);
          Stg[cur][r][slot] = (short)f2bf(aK[rf][j]);
          Stg[cur][r][slot + 2] = (short)f2bf(g * aV[rf][j]);
        }
      if (w == 0 && nl < 8) {
#pragma unroll
        for (int rf = 0; rf < 4; ++rf)
#pragma unroll
          for (int j = 0; j < 4; ++j)
            bsb[(row0 + rf * 16 + r4 + j) * 8 + nl] = (short)f2bf(aB[rf][j] * LOG2E);
      }
      if (ti > 0) {  // flush previous tile's KG — overlaps this tile
        const size_t rp = (size_t)(t0 + ti - 1) * 64;
        for (int u = tid; u < 2048; u += 512) {
          int r = u >> 5, o = (u & 31) * 8;
          *reinterpret_cast<bhalf8*>(KG + (rp + r) * KGROW + o) =
              *reinterpret_cast<const bhalf8*>(&Stg[cur ^ 1][r][o]);
        }
      }
      if (ti < 4) stage_write(Xs[cur ^ 1], ld, tid);
      __syncthreads();
      cur ^= 1;
    }
    {  // final flush: tile 4
      const size_t rp = (size_t)(t0 + 4) * 64;
      for (int u = tid; u < 2048; u += 512) {
        int r = u >> 5, o = (u & 31) * 8;
        *reinterpret_cast<bhalf8*>(KG + (rp + r) * KGROW + o) =
            *reinterpret_cast<const bhalf8*>(&Stg[cur ^ 1][r][o]);
      }
    }
  }
}

// ---------------- split-wave softmax attention: 2 edges/wave, 16B/lane gathers ----
__global__ __launch_bounds__(256) void k_attn(const uint2* __restrict__ Qp2,
                                              const uint4* __restrict__ KGp4,
                                              const short* __restrict__ bsb,
                                              const uint2* __restrict__ gtp2,
                                              const int* __restrict__ cntp,
                                              const ushort* __restrict__ elist,
                                              uint2* __restrict__ tmpp2) {
  const int wave = threadIdx.x >> 6;
  const int lane = threadIdx.x & 63;
  const int t = blockIdx.x * 4 + wave;  // 10000*4 == 40000
  const int p = lane & 31;
  const int h = p >> 2;
  const int hi = lane >> 5;

  uint2 qv = Qp2[(size_t)t * 32 + p];  // pre-scaled by 0.25*log2e
  float q0 = bflo(qv.x), q1 = bfhi(qv.x), q2 = bflo(qv.y), q3 = bfhi(qv.y);
  const int deg = min(cntp[t << 4], CAP);
  const int ebase = t * CAP;

  float ssum = 0.f, a0 = 0.f, a1 = 0.f, a2 = 0.f, a3 = 0.f;
  int i = 0;
  for (; i + 8 <= deg; i += 8) {
    int sv[4];
    uint4 kv[4];
    float bv[4], dd[4];
#pragma unroll
    for (int u = 0; u < 4; ++u) sv[u] = (int)elist[ebase + i + 2 * u + hi];
#pragma unroll
    for (int u = 0; u < 4; ++u) {
      kv[u] = KGp4[(size_t)sv[u] * 32 + p];
      bv[u] = bf2f(bsb[(size_t)sv[u] * 8 + h]);
    }
#pragma unroll
    for (int u = 0; u < 4; ++u)
      dd[u] = q0 * bflo(kv[u].x) + q1 * bfhi(kv[u].x) + q2 * bflo(kv[u].z) + q3 * bfhi(kv[u].z);
#pragma unroll
    for (int u = 0; u < 4; ++u) dd[u] += __shfl_xor(dd[u], 1);
#pragma unroll
    for (int u = 0; u < 4; ++u) dd[u] += __shfl_xor(dd[u], 2);
#pragma unroll
    for (int u = 0; u < 4; ++u) {
      float e = __builtin_amdgcn_exp2f(dd[u] + bv[u]);
      ssum += e;
      a0 = fmaf(e, bflo(kv[u].y), a0);
      a1 = fmaf(e, bfhi(kv[u].y), a1);
      a2 = fmaf(e, bflo(kv[u].w), a2);
      a3 = fmaf(e, bfhi(kv[u].w), a3);
    }
  }
  for (; i < deg; i += 2) {
    int idx = i + hi;
    float pen = 0.f;
    if (idx >= deg) { idx = deg - 1; pen = -1e30f; }  // odd tail: kill edge B
    int s = (int)elist[ebase + idx];
    uint4 kv = KGp4[(size_t)s * 32 + p];
    float bsv = bf2f(bsb[(size_t)s * 8 + h]);
    float d = q0 * bflo(kv.x) + q1 * bfhi(kv.x) + q2 * bflo(kv.z) + q3 * bfhi(kv.z);
    d += __shfl_xor(d, 1);
    d += __shfl_xor(d, 2);
    float e = __builtin_amdgcn_exp2f(d + bsv + pen);
    ssum += e;
    a0 = fmaf(e, bflo(kv.y), a0);
    a1 = fmaf(e, bfhi(kv.y), a1);
    a2 = fmaf(e, bflo(kv.w), a2);
    a3 = fmaf(e, bfhi(kv.w), a3);
  }
  ssum += __shfl_xor(ssum, 32);
  a0 += __shfl_xor(a0, 32);
  a1 += __shfl_xor(a1, 32);
  a2 += __shfl_xor(a2, 32);
  a3 += __shfl_xor(a3, 32);
  if (lane < 32) {
    float inv = 1.f / (ssum + 1e-12f);
    uint2 g2 = gtp2[(size_t)t * 32 + p];
    float o0 = bflo(g2.x) * a0 * inv;
    float o1 = bfhi(g2.x) * a1 * inv;
    float o2 = bflo(g2.y) * a2 * inv;
    float o3 = bfhi(g2.y) * a3 * inv;
    uint2 pk;
    pk.x = ((uint)f2bf(o0)) | (((uint)f2bf(o1)) << 16);
    pk.y = ((uint)f2bf(o2)) | (((uint)f2bf(o3)) << 16);
    tmpp2[(size_t)t * 32 + p] = pk;
  }
}

// ---------------- final GEMM: out = tmp @ Wo (fp32 out) ----------------
__device__ __forceinline__ void stage_rows_bf16(const short* __restrict__ X, size_t row0,
                                                short (*Xs)[136], int tid) {
  for (int i = tid; i < 64 * 32; i += 256) {
    int r = i >> 5, c4 = (i & 31) * 4;
    *reinterpret_cast<bhalf4*>(&Xs[r][c4]) =
        *reinterpret_cast<const bhalf4*>(X + (row0 + r) * 128 + c4);
  }
}

__device__ __forceinline__ void mfma_pass(const short (*Xs)[136], int wave, int lane,
                                          const short* __restrict__ WT, f4acc acc[8]) {
  const int rl = wave * 16 + (lane & 15);
  const int kg = (lane >> 4) * 8;
  const int nl = lane & 15;
#pragma unroll
  for (int ks = 0; ks < 4; ++ks) {
    bfrag a = *reinterpret_cast<const bfrag*>(&Xs[rl][ks * 32 + kg]);
#pragma unroll
    for (int nf = 0; nf < 8; ++nf) {
      bfrag b = *reinterpret_cast<const bfrag*>(WT + (size_t)(nf * 16 + nl) * 128 + ks * 32 + kg);
      acc[nf] = MFMA16(a, b, acc[nf]);
    }
  }
}

__global__ __launch_bounds__(256) void k_out(const short* __restrict__ tmpb,
                                             const short* __restrict__ WoT,
                                             float* __restrict__ out) {
  __shared__ short Xs[64][136];
  const int tid = threadIdx.x;
  const size_t row0 = (size_t)blockIdx.x * 64;
  stage_rows_bf16(tmpb, row0, Xs, tid);
  __syncthreads();
  const int wave = tid >> 6, lane = tid & 63;
  const int rbase = (int)row0 + wave * 16 + ((lane >> 4) << 2);
  const int cl = lane & 15;
  f4acc acc[8] = {};
  mfma_pass(Xs, wave, lane, WoT, acc);
#pragma unroll
  for (int nf = 0; nf < 8; ++nf)
#pragma unroll
    for (int j = 0; j < 4; ++j)
      out[(size_t)(rbase + j) * 128 + nf * 16 + cl] = acc[nf][j];
}

extern "C" void kernel_launch(void* const* d_in, const int* in_sizes, int n_in,
                              void* d_out, int out_size, void* d_ws, size_t ws_size,
                              hipStream_t stream) {
  const float* X_tgt = (const float*)d_in[0];
  const float* X_src = (const float*)d_in[1];
  const int* inc_tgt = (const int*)d_in[2];
  const int* inc_src = (const int*)d_in[3];
  const float* Wq    = (const float*)d_in[5];
  const float* Wkv   = (const float*)d_in[6];
  const float* Wbs   = (const float*)d_in[8];
  const float* Wgt_w = (const float*)d_in[9];
  const float* Wgt_b = (const float*)d_in[10];
  const float* Wgs_w = (const float*)d_in[11];
  const float* Wgs_b = (const float*)d_in[12];
  const float* Wo    = (const float*)d_in[13];
  float* out = (float*)d_out;

  char* ws = (char*)d_ws;
  short* Qb   = (short*)ws; ws += (size_t)NTGT * 128 * 2;
  short* KG   = (short*)ws; ws += (size_t)NSRC * KGROW * 2;
  short* gtb  = (short*)ws; ws += (size_t)NTGT * 128 * 2;
  short* tmpb = (short*)ws; ws += (size_t)NTGT * 128 * 2;
  short* bsb  = (short*)ws; ws += (size_t)NSRC * 8 * 2;
  int* cntp  = (int*)ws; ws += (size_t)NTGT * 16 * 4;  // 64B stride per counter
  ushort* elist = (ushort*)ws; ws += (size_t)NTGT * CAP * 2;
  short* WqT  = (short*)ws; ws += 128 * 128 * 2;
  short* WkT  = (short*)ws; ws += 128 * 128 * 2;
  short* WvT  = (short*)ws; ws += 128 * 128 * 2;
  short* WgtT = (short*)ws; ws += 128 * 128 * 2;
  short* WgsT = (short*)ws; ws += 128 * 128 * 2;
  short* WoT  = (short*)ws; ws += 128 * 128 * 2;
  short* WbsT = (short*)ws; ws += 16 * 128 * 2;

  k_prep<<<632, 256, 0, stream>>>(Wq, Wkv, Wgt_w, Wgs_w, Wo, Wbs, cntp,
                                  WqT, WkT, WvT, WgtT, WgsT, WoT, WbsT);
  k_fill<<<2560, 512, 0, stream>>>(inc_tgt, inc_src, cntp, elist);
  k_proj<<<250, 512, 0, stream>>>(X_tgt, X_src, WqT, WgtT, WkT, WvT, WgsT,
                                  WbsT, Wgt_b, Wgs_b, Qb, gtb, KG, bsb);
  k_attn<<<NTGT / 4, 256, 0, stream>>>((const uint2*)Qb, (const uint4*)KG, bsb,
                                       (const uint2*)gtb, cntp, elist, (uint2*)tmpb);
  k_out<<<NTGT / 64, 256, 0, stream>>>(tmpb, WoT, out);
}

// Round 19
// 124.845 us; speedup vs baseline: 1.0287x; 1.0287x over previous
//
#include <hip/hip_runtime.h>
#include <math.h>

#define NTGT 40000
#define NSRC 40000
#define NEDGE 640000
#define LOG2E 1.44269504088896f
#define KGROW 256  // shorts per KG row: 256 K/GV interleaved = 512B, 8 aligned lines
#define CAP 64     // max edges per target (Poisson(16), max~34; P(>63)~1e-17)

typedef __attribute__((ext_vector_type(8))) short bfrag;   // 8 bf16 (4 VGPRs)
typedef __attribute__((ext_vector_type(4))) short bhalf4;  // 8B
typedef __attribute__((ext_vector_type(8))) short bhalf8;  // 16B
typedef __attribute__((ext_vector_type(4))) float f4acc;   // MFMA accumulator

__device__ __forceinline__ ushort f2bf(float f) {
  uint u = __float_as_uint(f);
  u += 0x7fffu + ((u >> 16) & 1u);  // RNE
  return (ushort)(u >> 16);
}
__device__ __forceinline__ float bflo(uint u) { return __uint_as_float(u << 16); }
__device__ __forceinline__ float bfhi(uint u) { return __uint_as_float(u & 0xffff0000u); }
__device__ __forceinline__ float bf2f(short s) { return __uint_as_float(((uint)(ushort)s) << 16); }
__device__ __forceinline__ float sigmoidf_fast(float x) { return 1.0f / (1.0f + __expf(-x)); }

// ---------------- prep: weight transpose/convert + counter zeroing ----------------
// blocks 0..5: square mats; 6: Wbs bias mat; 7..631: zero cntp (625*1024 ints)
__global__ __launch_bounds__(256) void k_prep(const float* __restrict__ Wq,
                                              const float* __restrict__ Wkv,
                                              const float* __restrict__ Wgt_w,
                                              const float* __restrict__ Wgs_w,
                                              const float* __restrict__ Wo,
                                              const float* __restrict__ Wbs,
                                              int* __restrict__ cntp,
                                              short* __restrict__ WqT, short* __restrict__ WkT,
                                              short* __restrict__ WvT, short* __restrict__ WgtT,
                                              short* __restrict__ WgsT, short* __restrict__ WoT,
                                              short* __restrict__ WbsT) {
  const int b = blockIdx.x;
  const int tid = threadIdx.x;
  if (b >= 7) {
    int i = (b - 7) * 1024 + tid * 4;  // 625*1024 = 640000 = 40000*16 exact
    int4 z = {0, 0, 0, 0};
    *reinterpret_cast<int4*>(cntp + i) = z;
    return;
  }
  if (b == 6) {
    for (int idx = tid; idx < 16 * 128; idx += 256) {
      int n = idx >> 7, k = idx & 127;
      WbsT[idx] = (n < 8) ? (short)f2bf(Wbs[k * 8 + n]) : (short)0;
    }
    return;
  }
  __shared__ short T[128][136];
  const float* src;
  int ld, off;
  short* dst;
  switch (b) {
    case 0: src = Wq;    ld = 128; off = 0;   dst = WqT;  break;
    case 1: src = Wkv;   ld = 256; off = 0;   dst = WkT;  break;
    case 2: src = Wkv;   ld = 256; off = 128; dst = WvT;  break;
    case 3: src = Wgt_w; ld = 128; off = 0;   dst = WgtT; break;
    case 4: src = Wgs_w; ld = 128; off = 0;   dst = WgsT; break;
    default:src = Wo;    ld = 128; off = 0;   dst = WoT;  break;
  }
  for (int i = tid; i < 128 * 32; i += 256) {
    int k = i >> 5, c4 = (i & 31) * 4;
    float4 v = *reinterpret_cast<const float4*>(src + (size_t)k * ld + off + c4);
    T[c4 + 0][k] = (short)f2bf(v.x);
    T[c4 + 1][k] = (short)f2bf(v.y);
    T[c4 + 2][k] = (short)f2bf(v.z);
    T[c4 + 3][k] = (short)f2bf(v.w);
  }
  __syncthreads();
  for (int u = tid; u < 128 * 16; u += 256) {
    int n = u >> 4, o = (u & 15) * 8;
    *reinterpret_cast<bhalf8*>(dst + (size_t)n * 128 + o) =
        *reinterpret_cast<const bhalf8*>(&T[n][o]);
  }
}

// ---------------- XCD-partitioned bucket fill ----------------
__global__ __launch_bounds__(512) void k_fill(const int* __restrict__ inc_tgt,
                                              const int* __restrict__ inc_src,
                                              int* __restrict__ cntp,
                                              ushort* __restrict__ elist) {
  const int tid = threadIdx.x;
  const int part = blockIdx.x & 7;
  const int ebase = (blockIdx.x >> 3) * 2000;  // 320 chunks * 2000 = 640000 exact
#pragma unroll
  for (int k = 0; k < 4; ++k) {
    int off = k * 512 + tid;
    if (off < 2000) {
      int e = ebase + off;
      int t = inc_tgt[e];
      if ((t & 7) == part) {
        int pos = atomicAdd(&cntp[t << 4], 1);
        pos = min(pos, CAP - 1);  // never triggers; guards OOB
        elist[t * CAP + pos] = (ushort)inc_src[e];
      }
    }
  }
}

#define MFMA16(a, b, c) __builtin_amdgcn_mfma_f32_16x16x32_bf16(a, b, c, 0, 0, 0)

// ---------------- projections: double-buffered, ONE barrier per tile ----------------
__device__ __forceinline__ void stage_issue(const float* __restrict__ X, size_t row0,
                                            float4 ld[4], int tid) {
#pragma unroll
  for (int it = 0; it < 4; ++it) {
    int i = it * 512 + tid;
    int r = i >> 5, c4 = (i & 31) * 4;
    ld[it] = *reinterpret_cast<const float4*>(X + (row0 + r) * 128 + c4);
  }
}
__device__ __forceinline__ void stage_write(short (*Xs)[136], const float4 ld[4], int tid) {
#pragma unroll
  for (int it = 0; it < 4; ++it) {
    int i = it * 512 + tid;
    int r = i >> 5, c4 = (i & 31) * 4;
    bhalf4 o;
    o[0] = (short)f2bf(ld[it].x); o[1] = (short)f2bf(ld[it].y);
    o[2] = (short)f2bf(ld[it].z); o[3] = (short)f2bf(ld[it].w);
    *reinterpret_cast<bhalf4*>(&Xs[r][c4]) = o;
  }
}

__global__ __launch_bounds__(512) void k_proj(const float* __restrict__ Xt,
                                              const float* __restrict__ Xsrc,
                                              const short* __restrict__ WqT,
                                              const short* __restrict__ WgtT,
                                              const short* __restrict__ WkT,
                                              const short* __restrict__ WvT,
                                              const short* __restrict__ WgsT,
                                              const short* __restrict__ WbsT,
                                              const float* __restrict__ Wgt_b,
                                              const float* __restrict__ Wgs_b,
                                              short* __restrict__ Qb, short* __restrict__ gtb,
                                              short* __restrict__ KG,
                                              short* __restrict__ bsb) {
  const int tid = threadIdx.x;
  __shared__ short Xs[2][64][136];   // 34.8 KB
  __shared__ short Stg[2][64][256];  // 64 KB  (98.8 KB total -> 1 block/CU)
  const int w = tid >> 6, lane = tid & 63;
  const int nl = lane & 15;
  const int kg = (lane >> 4) * 8;
  const int r4 = (lane >> 4) * 4;
  const int c0 = w * 16;
  const bool is_src = blockIdx.x >= 125;
  const int t0 = (is_src ? blockIdx.x - 125 : blockIdx.x) * 5;
  const float* X = is_src ? Xsrc : Xt;

  if (!is_src) {
    bfrag Bq[4], Bg[4];
#pragma unroll
    for (int ks = 0; ks < 4; ++ks) {
      const size_t wo = (size_t)(c0 + nl) * 128 + ks * 32 + kg;
      Bq[ks] = *reinterpret_cast<const bfrag*>(WqT + wo);
      Bg[ks] = *reinterpret_cast<const bfrag*>(WgtT + wo);
    }
    const int c = c0 + nl;
    const float gb = Wgt_b[c];
    {
      float4 ld[4];
      stage_issue(X, (size_t)t0 * 64, ld, tid);
      stage_write(Xs[0], ld, tid);
    }
    __syncthreads();
    int cur = 0;
    for (int ti = 0; ti < 5; ++ti) {
      const size_t row0 = (size_t)(t0 + ti) * 64;
      float4 ld[4];
      if (ti < 4) stage_issue(X, row0 + 64, ld, tid);
      f4acc aQ[4] = {}, aG[4] = {};
#pragma unroll
      for (int ks = 0; ks < 4; ++ks) {
        const int ko = ks * 32 + kg;
        bfrag a0 = *reinterpret_cast<const bfrag*>(&Xs[cur][nl][ko]);
        bfrag a1 = *reinterpret_cast<const bfrag*>(&Xs[cur][16 + nl][ko]);
        bfrag a2 = *reinterpret_cast<const bfrag*>(&Xs[cur][32 + nl][ko]);
        bfrag a3 = *reinterpret_cast<const bfrag*>(&Xs[cur][48 + nl][ko]);
        aQ[0] = MFMA16(a0, Bq[ks], aQ[0]);
        aQ[1] = MFMA16(a1, Bq[ks], aQ[1]);
        aQ[2] = MFMA16(a2, Bq[ks], aQ[2]);
        aQ[3] = MFMA16(a3, Bq[ks], aQ[3]);
        aG[0] = MFMA16(a0, Bg[ks], aG[0]);
        aG[1] = MFMA16(a1, Bg[ks], aG[1]);
        aG[2] = MFMA16(a2, Bg[ks], aG[2]);
        aG[3] = MFMA16(a3, Bg[ks], aG[3]);
      }
#pragma unroll
      for (int rf = 0; rf < 4; ++rf)
#pragma unroll
        for (int j = 0; j < 4; ++j) {
          int r = rf * 16 + r4 + j;
          Stg[cur][r][c] = (short)f2bf(aQ[rf][j] * (0.25f * LOG2E));
          Stg[cur][r][128 + c] = (short)f2bf(sigmoidf_fast(aG[rf][j] + gb));
        }
      if (ti > 0) {  // flush previous tile (other Stg buffer) — overlaps this tile
        const size_t rp = (size_t)(t0 + ti - 1) * 64;
        for (int u = tid; u < 1024; u += 512) {
          int r = u >> 4, o = (u & 15) * 8;
          *reinterpret_cast<bhalf8*>(Qb + (rp + r) * 128 + o) =
              *reinterpret_cast<const bhalf8*>(&Stg[cur ^ 1][r][o]);
          *reinterpret_cast<bhalf8*>(gtb + (rp + r) * 128 + o) =
              *reinterpret_cast<const bhalf8*>(&Stg[cur ^ 1][r][128 + o]);
        }
      }
      if (ti < 4) stage_write(Xs[cur ^ 1], ld, tid);
      __syncthreads();
      cur ^= 1;
    }
    {  // final flush: tile 4 lives in Stg[cur^1]
      const size_t rp = (size_t)(t0 + 4) * 64;
      for (int u = tid; u < 1024; u += 512) {
        int r = u >> 4, o = (u & 15) * 8;
        *reinterpret_cast<bhalf8*>(Qb + (rp + r) * 128 + o) =
            *reinterpret_cast<const bhalf8*>(&Stg[cur ^ 1][r][o]);
        *reinterpret_cast<bhalf8*>(gtb + (rp + r) * 128 + o) =
            *reinterpret_cast<const bhalf8*>(&Stg[cur ^ 1][r][128 + o]);
      }
    }
  } else {
    bfrag Bk[4], Bv[4], Bg[4], Bb[4];
#pragma unroll
    for (int ks = 0; ks < 4; ++ks) {
      const size_t wo = (size_t)(c0 + nl) * 128 + ks * 32 + kg;
      Bk[ks] = *reinterpret_cast<const bfrag*>(WkT + wo);
      Bv[ks] = *reinterpret_cast<const bfrag*>(WvT + wo);
      Bg[ks] = *reinterpret_cast<const bfrag*>(WgsT + wo);
      Bb[ks] = *reinterpret_cast<const bfrag*>(WbsT + (size_t)nl * 128 + ks * 32 + kg);
    }
    const int c = c0 + nl;
    const int slot = (c >> 1) * 4 + (c & 1);
    const float gb = Wgs_b[c];
    {
      float4 ld[4];
      stage_issue(X, (size_t)t0 * 64, ld, tid);
      stage_write(Xs[0], ld, tid);
    }
    __syncthreads();
    int cur = 0;
    for (int ti = 0; ti < 5; ++ti) {
      const size_t row0 = (size_t)(t0 + ti) * 64;
      float4 ld[4];
      if (ti < 4) stage_issue(X, row0 + 64, ld, tid);
      f4acc aK[4] = {}, aV[4] = {}, aG[4] = {}, aB[4] = {};
#pragma unroll
      for (int ks = 0; ks < 4; ++ks) {
        const int ko = ks * 32 + kg;
        bfrag a0 = *reinterpret_cast<const bfrag*>(&Xs[cur][nl][ko]);
        bfrag a1 = *reinterpret_cast<const bfrag*>(&Xs[cur][16 + nl][ko]);
        bfrag a2 = *reinterpret_cast<const bfrag*>(&Xs[cur][32 + nl][ko]);
        bfrag a3 = *reinterpret_cast<const bfrag*>(&Xs[cur][48 + nl][ko]);
        aK[0] = MFMA16(a0, Bk[ks], aK[0]);
        aK[1] = MFMA16(a1, Bk[ks], aK[1]);
        aK[2] = MFMA16(a2, Bk[ks], aK[2]);
        aK[3] = MFMA16(a3, Bk[ks], aK[3]);
        aV[0] = MFMA16(a0, Bv[ks], aV[0]);
        aV[1] = MFMA16(a1, Bv[ks], aV[1]);
        aV[2] = MFMA16(a2, Bv[ks], aV[2]);
        aV[3] = MFMA16(a3, Bv[ks], aV[3]);
        aG[0] = MFMA16(a0, Bg[ks], aG[0]);
        aG[1] = MFMA16(a1, Bg[ks], aG[1]);
        aG[2] = MFMA16(a2, Bg[ks], aG[2]);
        aG[3] = MFMA16(a3, Bg[ks], aG[3]);
        if (w == 0) {
          aB[0] = MFMA16(a0, Bb[ks], aB[0]);
          aB[1] = MFMA16(a1, Bb[ks], aB[1]);
          aB[2] = MFMA16(a2, Bb[ks], aB[2]);
          aB[3] = MFMA16(a3, Bb[ks], aB[3]);
        }
      }
#pragma unroll
      for (int rf = 0; rf < 4; ++rf)
#pragma unroll
        for (int j = 0; j < 4; ++j) {
          int r = rf * 16 + r4 + j;
          float g = sigmoidf_fast(aG[rf][j] + gb);
          Stg[cur][r][slot] = (short)f2bf(aK[rf][j]);
          Stg[cur][r][slot + 2] = (short)f2bf(g * aV[rf][j]);
        }
      if (w == 0 && nl < 8) {
#pragma unroll
        for (int rf = 0; rf < 4; ++rf)
#pragma unroll
          for (int j = 0; j < 4; ++j)
            bsb[(row0 + rf * 16 + r4 + j) * 8 + nl] = (short)f2bf(aB[rf][j] * LOG2E);
      }
      if (ti > 0) {  // flush previous tile's KG — overlaps this tile
        const size_t rp = (size_t)(t0 + ti - 1) * 64;
        for (int u = tid; u < 2048; u += 512) {
          int r = u >> 5, o = (u & 31) * 8;
          *reinterpret_cast<bhalf8*>(KG + (rp + r) * KGROW + o) =
              *reinterpret_cast<const bhalf8*>(&Stg[cur ^ 1][r][o]);
        }
      }
      if (ti < 4) stage_write(Xs[cur ^ 1], ld, tid);
      __syncthreads();
      cur ^= 1;
    }
    {  // final flush: tile 4
      const size_t rp = (size_t)(t0 + 4) * 64;
      for (int u = tid; u < 2048; u += 512) {
        int r = u >> 5, o = (u & 31) * 8;
        *reinterpret_cast<bhalf8*>(KG + (rp + r) * KGROW + o) =
            *reinterpret_cast<const bhalf8*>(&Stg[cur ^ 1][r][o]);
      }
    }
  }
}

// ---------------- fused attention + output GEMM ----------------
// 512 threads = 8 waves; block owns 64 targets; wave w handles targets w*8..w*8+7.
// Attention results -> bf16 LDS tile T[64][136]; barrier; waves 0..3 MFMA vs WoT.
__device__ __forceinline__ void mfma_pass(const short (*Xs)[136], int wave, int lane,
                                          const short* __restrict__ WT, f4acc acc[8]) {
  const int rl = wave * 16 + (lane & 15);
  const int kg = (lane >> 4) * 8;
  const int nl = lane & 15;
#pragma unroll
  for (int ks = 0; ks < 4; ++ks) {
    bfrag a = *reinterpret_cast<const bfrag*>(&Xs[rl][ks * 32 + kg]);
#pragma unroll
    for (int nf = 0; nf < 8; ++nf) {
      bfrag b = *reinterpret_cast<const bfrag*>(WT + (size_t)(nf * 16 + nl) * 128 + ks * 32 + kg);
      acc[nf] = MFMA16(a, b, acc[nf]);
    }
  }
}

__global__ __launch_bounds__(512) void k_attn(const uint2* __restrict__ Qp2,
                                              const uint4* __restrict__ KGp4,
                                              const short* __restrict__ bsb,
                                              const uint2* __restrict__ gtp2,
                                              const int* __restrict__ cntp,
                                              const ushort* __restrict__ elist,
                                              const short* __restrict__ WoT,
                                              float* __restrict__ out) {
  __shared__ short T[64][136];
  const int tid = threadIdx.x;
  const int w = tid >> 6;
  const int lane = tid & 63;
  const int p = lane & 31;
  const int h = p >> 2;
  const int hi = lane >> 5;
  const int tb = blockIdx.x * 64;  // 625 * 64 == 40000 exact

  for (int tt = 0; tt < 8; ++tt) {
    const int t = tb + w * 8 + tt;
    uint2 qv = Qp2[(size_t)t * 32 + p];  // pre-scaled by 0.25*log2e
    float q0 = bflo(qv.x), q1 = bfhi(qv.x), q2 = bflo(qv.y), q3 = bfhi(qv.y);
    const int deg = min(cntp[t << 4], CAP);
    const int ebase = t * CAP;

    float ssum = 0.f, a0 = 0.f, a1 = 0.f, a2 = 0.f, a3 = 0.f;
    int i = 0;
    for (; i + 8 <= deg; i += 8) {
      int sv[4];
      uint4 kv[4];
      float bv[4], dd[4];
#pragma unroll
      for (int u = 0; u < 4; ++u) sv[u] = (int)elist[ebase + i + 2 * u + hi];
#pragma unroll
      for (int u = 0; u < 4; ++u) {
        kv[u] = KGp4[(size_t)sv[u] * 32 + p];
        bv[u] = bf2f(bsb[(size_t)sv[u] * 8 + h]);
      }
#pragma unroll
      for (int u = 0; u < 4; ++u)
        dd[u] = q0 * bflo(kv[u].x) + q1 * bfhi(kv[u].x) + q2 * bflo(kv[u].z) + q3 * bfhi(kv[u].z);
#pragma unroll
      for (int u = 0; u < 4; ++u) dd[u] += __shfl_xor(dd[u], 1);
#pragma unroll
      for (int u = 0; u < 4; ++u) dd[u] += __shfl_xor(dd[u], 2);
#pragma unroll
      for (int u = 0; u < 4; ++u) {
        float e = __builtin_amdgcn_exp2f(dd[u] + bv[u]);
        ssum += e;
        a0 = fmaf(e, bflo(kv[u].y), a0);
        a1 = fmaf(e, bfhi(kv[u].y), a1);
        a2 = fmaf(e, bflo(kv[u].w), a2);
        a3 = fmaf(e, bfhi(kv[u].w), a3);
      }
    }
    for (; i < deg; i += 2) {
      int idx = i + hi;
      float pen = 0.f;
      if (idx >= deg) { idx = deg - 1; pen = -1e30f; }  // odd tail: kill edge B
      int s = (int)elist[ebase + idx];
      uint4 kv = KGp4[(size_t)s * 32 + p];
      float bsv = bf2f(bsb[(size_t)s * 8 + h]);
      float d = q0 * bflo(kv.x) + q1 * bfhi(kv.x) + q2 * bflo(kv.z) + q3 * bfhi(kv.z);
      d += __shfl_xor(d, 1);
      d += __shfl_xor(d, 2);
      float e = __builtin_amdgcn_exp2f(d + bsv + pen);
      ssum += e;
      a0 = fmaf(e, bflo(kv.y), a0);
      a1 = fmaf(e, bfhi(kv.y), a1);
      a2 = fmaf(e, bflo(kv.w), a2);
      a3 = fmaf(e, bfhi(kv.w), a3);
    }
    ssum += __shfl_xor(ssum, 32);
    a0 += __shfl_xor(a0, 32);
    a1 += __shfl_xor(a1, 32);
    a2 += __shfl_xor(a2, 32);
    a3 += __shfl_xor(a3, 32);
    if (lane < 32) {
      float inv = 1.f / (ssum + 1e-12f);
      uint2 g2 = gtp2[(size_t)t * 32 + p];
      bhalf4 pk;
      pk[0] = (short)f2bf(bflo(g2.x) * a0 * inv);
      pk[1] = (short)f2bf(bfhi(g2.x) * a1 * inv);
      pk[2] = (short)f2bf(bflo(g2.y) * a2 * inv);
      pk[3] = (short)f2bf(bfhi(g2.y) * a3 * inv);
      *reinterpret_cast<bhalf4*>(&T[w * 8 + tt][p * 4]) = pk;
    }
  }
  __syncthreads();
  if (w < 4) {  // output GEMM: rows tb..tb+63 = T @ Wo
    f4acc acc[8] = {};
    mfma_pass(T, w, lane, WoT, acc);
    const int rbase = tb + w * 16 + ((lane >> 4) << 2);
    const int cl = lane & 15;
#pragma unroll
    for (int nf = 0; nf < 8; ++nf)
#pragma unroll
      for (int j = 0; j < 4; ++j)
        out[(size_t)(rbase + j) * 128 + nf * 16 + cl] = acc[nf][j];
  }
}

extern "C" void kernel_launch(void* const* d_in, const int* in_sizes, int n_in,
                              void* d_out, int out_size, void* d_ws, size_t ws_size,
                              hipStream_t stream) {
  const float* X_tgt = (const float*)d_in[0];
  const float* X_src = (const float*)d_in[1];
  const int* inc_tgt = (const int*)d_in[2];
  const int* inc_src = (const int*)d_in[3];
  const float* Wq    = (const float*)d_in[5];
  const float* Wkv   = (const float*)d_in[6];
  const float* Wbs   = (const float*)d_in[8];
  const float* Wgt_w = (const float*)d_in[9];
  const float* Wgt_b = (const float*)d_in[10];
  const float* Wgs_w = (const float*)d_in[11];
  const float* Wgs_b = (const float*)d_in[12];
  const float* Wo    = (const float*)d_in[13];
  float* out = (float*)d_out;

  char* ws = (char*)d_ws;
  short* Qb   = (short*)ws; ws += (size_t)NTGT * 128 * 2;
  short* KG   = (short*)ws; ws += (size_t)NSRC * KGROW * 2;
  short* gtb  = (short*)ws; ws += (size_t)NTGT * 128 * 2;
  short* bsb  = (short*)ws; ws += (size_t)NSRC * 8 * 2;
  int* cntp  = (int*)ws; ws += (size_t)NTGT * 16 * 4;  // 64B stride per counter
  ushort* elist = (ushort*)ws; ws += (size_t)NTGT * CAP * 2;
  short* WqT  = (short*)ws; ws += 128 * 128 * 2;
  short* WkT  = (short*)ws; ws += 128 * 128 * 2;
  short* WvT  = (short*)ws; ws += 128 * 128 * 2;
  short* WgtT = (short*)ws; ws += 128 * 128 * 2;
  short* WgsT = (short*)ws; ws += 128 * 128 * 2;
  short* WoT  = (short*)ws; ws += 128 * 128 * 2;
  short* WbsT = (short*)ws; ws += 16 * 128 * 2;

  k_prep<<<632, 256, 0, stream>>>(Wq, Wkv, Wgt_w, Wgs_w, Wo, Wbs, cntp,
                                  WqT, WkT, WvT, WgtT, WgsT, WoT, WbsT);
  k_fill<<<2560, 512, 0, stream>>>(inc_tgt, inc_src, cntp, elist);
  k_proj<<<250, 512, 0, stream>>>(X_tgt, X_src, WqT, WgtT, WkT, WvT, WgsT,
                                  WbsT, Wgt_b, Wgs_b, Qb, gtb, KG, bsb);
  k_attn<<<NTGT / 64, 512, 0, stream>>>((const uint2*)Qb, (const uint4*)KG, bsb,
                                        (const uint2*)gtb, cntp, elist, WoT, out);
}

// Round 20
// 120.576 us; speedup vs baseline: 1.0651x; 1.0354x over previous
//
#include <hip/hip_runtime.h>
#include <math.h>

#define NTGT 40000
#define NSRC 40000
#define NEDGE 640000
#define LOG2E 1.44269504088896f
#define KGROW 256  // shorts per KG row: 256 K/GV interleaved = 512B, 8 aligned lines
#define CAP 64     // max edges per target (Poisson(16), max~34; P(>63)~1e-17)

typedef __attribute__((ext_vector_type(8))) short bfrag;   // 8 bf16 (4 VGPRs)
typedef __attribute__((ext_vector_type(4))) short bhalf4;  // 8B
typedef __attribute__((ext_vector_type(8))) short bhalf8;  // 16B
typedef __attribute__((ext_vector_type(4))) float f4acc;   // MFMA accumulator

__device__ __forceinline__ ushort f2bf(float f) {
  uint u = __float_as_uint(f);
  u += 0x7fffu + ((u >> 16) & 1u);  // RNE
  return (ushort)(u >> 16);
}
__device__ __forceinline__ float bflo(uint u) { return __uint_as_float(u << 16); }
__device__ __forceinline__ float bfhi(uint u) { return __uint_as_float(u & 0xffff0000u); }
__device__ __forceinline__ float bf2f(short s) { return __uint_as_float(((uint)(ushort)s) << 16); }
__device__ __forceinline__ float sigmoidf_fast(float x) { return 1.0f / (1.0f + __expf(-x)); }

// ---------------- prep: weight transpose/convert + counter zeroing ----------------
// blocks 0..5: square mats; 6: Wbs bias mat; 7..631: zero cntp (625*1024 ints)
__global__ __launch_bounds__(256) void k_prep(const float* __restrict__ Wq,
                                              const float* __restrict__ Wkv,
                                              const float* __restrict__ Wgt_w,
                                              const float* __restrict__ Wgs_w,
                                              const float* __restrict__ Wo,
                                              const float* __restrict__ Wbs,
                                              int* __restrict__ cntp,
                                              short* __restrict__ WqT, short* __restrict__ WkT,
                                              short* __restrict__ WvT, short* __restrict__ WgtT,
                                              short* __restrict__ WgsT, short* __restrict__ WoT,
                                              short* __restrict__ WbsT) {
  const int b = blockIdx.x;
  const int tid = threadIdx.x;
  if (b >= 7) {
    int i = (b - 7) * 1024 + tid * 4;  // 625*1024 = 640000 = 40000*16 exact
    int4 z = {0, 0, 0, 0};
    *reinterpret_cast<int4*>(cntp + i) = z;
    return;
  }
  if (b == 6) {
    for (int idx = tid; idx < 16 * 128; idx += 256) {
      int n = idx >> 7, k = idx & 127;
      WbsT[idx] = (n < 8) ? (short)f2bf(Wbs[k * 8 + n]) : (short)0;
    }
    return;
  }
  __shared__ short T[128][136];
  const float* src;
  int ld, off;
  short* dst;
  switch (b) {
    case 0: src = Wq;    ld = 128; off = 0;   dst = WqT;  break;
    case 1: src = Wkv;   ld = 256; off = 0;   dst = WkT;  break;
    case 2: src = Wkv;   ld = 256; off = 128; dst = WvT;  break;
    case 3: src = Wgt_w; ld = 128; off = 0;   dst = WgtT; break;
    case 4: src = Wgs_w; ld = 128; off = 0;   dst = WgsT; break;
    default:src = Wo;    ld = 128; off = 0;   dst = WoT;  break;
  }
  for (int i = tid; i < 128 * 32; i += 256) {
    int k = i >> 5, c4 = (i & 31) * 4;
    float4 v = *reinterpret_cast<const float4*>(src + (size_t)k * ld + off + c4);
    T[c4 + 0][k] = (short)f2bf(v.x);
    T[c4 + 1][k] = (short)f2bf(v.y);
    T[c4 + 2][k] = (short)f2bf(v.z);
    T[c4 + 3][k] = (short)f2bf(v.w);
  }
  __syncthreads();
  for (int u = tid; u < 128 * 16; u += 256) {
    int n = u >> 4, o = (u & 15) * 8;
    *reinterpret_cast<bhalf8*>(dst + (size_t)n * 128 + o) =
        *reinterpret_cast<const bhalf8*>(&T[n][o]);
  }
}

// ---------------- XCD-partitioned bucket fill ----------------
__global__ __launch_bounds__(512) void k_fill(const int* __restrict__ inc_tgt,
                                              const int* __restrict__ inc_src,
                                              int* __restrict__ cntp,
                                              ushort* __restrict__ elist) {
  const int tid = threadIdx.x;
  const int part = blockIdx.x & 7;
  const int ebase = (blockIdx.x >> 3) * 2000;  // 320 chunks * 2000 = 640000 exact
#pragma unroll
  for (int k = 0; k < 4; ++k) {
    int off = k * 512 + tid;
    if (off < 2000) {
      int e = ebase + off;
      int t = inc_tgt[e];
      if ((t & 7) == part) {
        int pos = atomicAdd(&cntp[t << 4], 1);
        pos = min(pos, CAP - 1);  // never triggers; guards OOB
        elist[t * CAP + pos] = (ushort)inc_src[e];
      }
    }
  }
}

#define MFMA16(a, b, c) __builtin_amdgcn_mfma_f32_16x16x32_bf16(a, b, c, 0, 0, 0)

// ---------------- projections: double-buffered, ONE barrier per tile ----------------
__device__ __forceinline__ void stage_issue(const float* __restrict__ X, size_t row0,
                                            float4 ld[4], int tid) {
#pragma unroll
  for (int it = 0; it < 4; ++it) {
    int i = it * 512 + tid;
    int r = i >> 5, c4 = (i & 31) * 4;
    ld[it] = *reinterpret_cast<const float4*>(X + (row0 + r) * 128 + c4);
  }
}
__device__ __forceinline__ void stage_write(short (*Xs)[136], const float4 ld[4], int tid) {
#pragma unroll
  for (int it = 0; it < 4; ++it) {
    int i = it * 512 + tid;
    int r = i >> 5, c4 = (i & 31) * 4;
    bhalf4 o;
    o[0] = (short)f2bf(ld[it].x); o[1] = (short)f2bf(ld[it].y);
    o[2] = (short)f2bf(ld[it].z); o[3] = (short)f2bf(ld[it].w);
    *reinterpret_cast<bhalf4*>(&Xs[r][c4]) = o;
  }
}

__global__ __launch_bounds__(512) void k_proj(const float* __restrict__ Xt,
                                              const float* __restrict__ Xsrc,
                                              const short* __restrict__ WqT,
                                              const short* __restrict__ WgtT,
                                              const short* __restrict__ WkT,
                                              const short* __restrict__ WvT,
                                              const short* __restrict__ WgsT,
                                              const short* __restrict__ WbsT,
                                              const float* __restrict__ Wgt_b,
                                              const float* __restrict__ Wgs_b,
                                              short* __restrict__ Qb, short* __restrict__ gtb,
                                              short* __restrict__ KG,
                                              short* __restrict__ bsb) {
  const int tid = threadIdx.x;
  __shared__ short Xs[2][64][136];   // 34.8 KB
  __shared__ short Stg[2][64][256];  // 64 KB  (98.8 KB total -> 1 block/CU)
  const int w = tid >> 6, lane = tid & 63;
  const int nl = lane & 15;
  const int kg = (lane >> 4) * 8;
  const int r4 = (lane >> 4) * 4;
  const int c0 = w * 16;
  const bool is_src = blockIdx.x >= 125;
  const int t0 = (is_src ? blockIdx.x - 125 : blockIdx.x) * 5;
  const float* X = is_src ? Xsrc : Xt;

  if (!is_src) {
    bfrag Bq[4], Bg[4];
#pragma unroll
    for (int ks = 0; ks < 4; ++ks) {
      const size_t wo = (size_t)(c0 + nl) * 128 + ks * 32 + kg;
      Bq[ks] = *reinterpret_cast<const bfrag*>(WqT + wo);
      Bg[ks] = *reinterpret_cast<const bfrag*>(WgtT + wo);
    }
    const int c = c0 + nl;
    const float gb = Wgt_b[c];
    {
      float4 ld[4];
      stage_issue(X, (size_t)t0 * 64, ld, tid);
      stage_write(Xs[0], ld, tid);
    }
    __syncthreads();
    int cur = 0;
    for (int ti = 0; ti < 5; ++ti) {
      const size_t row0 = (size_t)(t0 + ti) * 64;
      float4 ld[4];
      if (ti < 4) stage_issue(X, row0 + 64, ld, tid);
      f4acc aQ[4] = {}, aG[4] = {};
#pragma unroll
      for (int ks = 0; ks < 4; ++ks) {
        const int ko = ks * 32 + kg;
        bfrag a0 = *reinterpret_cast<const bfrag*>(&Xs[cur][nl][ko]);
        bfrag a1 = *reinterpret_cast<const bfrag*>(&Xs[cur][16 + nl][ko]);
        bfrag a2 = *reinterpret_cast<const bfrag*>(&Xs[cur][32 + nl][ko]);
        bfrag a3 = *reinterpret_cast<const bfrag*>(&Xs[cur][48 + nl][ko]);
        aQ[0] = MFMA16(a0, Bq[ks], aQ[0]);
        aQ[1] = MFMA16(a1, Bq[ks], aQ[1]);
        aQ[2] = MFMA16(a2, Bq[ks], aQ[2]);
        aQ[3] = MFMA16(a3, Bq[ks], aQ[3]);
        aG[0] = MFMA16(a0, Bg[ks], aG[0]);
        aG[1] = MFMA16(a1, Bg[ks], aG[1]);
        aG[2] = MFMA16(a2, Bg[ks], aG[2]);
        aG[3] = MFMA16(a3, Bg[ks], aG[3]);
      }
#pragma unroll
      for (int rf = 0; rf < 4; ++rf)
#pragma unroll
        for (int j = 0; j < 4; ++j) {
          int r = rf * 16 + r4 + j;
          Stg[cur][r][c] = (short)f2bf(aQ[rf][j] * (0.25f * LOG2E));
          Stg[cur][r][128 + c] = (short)f2bf(sigmoidf_fast(aG[rf][j] + gb));
        }
      if (ti > 0) {  // flush previous tile (other Stg buffer) — overlaps this tile
        const size_t rp = (size_t)(t0 + ti - 1) * 64;
        for (int u = tid; u < 1024; u += 512) {
          int r = u >> 4, o = (u & 15) * 8;
          *reinterpret_cast<bhalf8*>(Qb + (rp + r) * 128 + o) =
              *reinterpret_cast<const bhalf8*>(&Stg[cur ^ 1][r][o]);
          *reinterpret_cast<bhalf8*>(gtb + (rp + r) * 128 + o) =
              *reinterpret_cast<const bhalf8*>(&Stg[cur ^ 1][r][128 + o]);
        }
      }
      if (ti < 4) stage_write(Xs[cur ^ 1], ld, tid);
      __syncthreads();
      cur ^= 1;
    }
    {  // final flush: tile 4 lives in Stg[cur^1]
      const size_t rp = (size_t)(t0 + 4) * 64;
      for (int u = tid; u < 1024; u += 512) {
        int r = u >> 4, o = (u & 15) * 8;
        *reinterpret_cast<bhalf8*>(Qb + (rp + r) * 128 + o) =
            *reinterpret_cast<const bhalf8*>(&Stg[cur ^ 1][r][o]);
        *reinterpret_cast<bhalf8*>(gtb + (rp + r) * 128 + o) =
            *reinterpret_cast<const bhalf8*>(&Stg[cur ^ 1][r][128 + o]);
      }
    }
  } else {
    bfrag Bk[4], Bv[4], Bg[4], Bb[4];
#pragma unroll
    for (int ks = 0; ks < 4; ++ks) {
      const size_t wo = (size_t)(c0 + nl) * 128 + ks * 32 + kg;
      Bk[ks] = *reinterpret_cast<const bfrag*>(WkT + wo);
      Bv[ks] = *reinterpret_cast<const bfrag*>(WvT + wo);
      Bg[ks] = *reinterpret_cast<const bfrag*>(WgsT + wo);
      Bb[ks] = *reinterpret_cast<const bfrag*>(WbsT + (size_t)nl * 128 + ks * 32 + kg);
    }
    const int c = c0 + nl;
    const int slot = (c >> 1) * 4 + (c & 1);
    const float gb = Wgs_b[c];
    {
      float4 ld[4];
      stage_issue(X, (size_t)t0 * 64, ld, tid);
      stage_write(Xs[0], ld, tid);
    }
    __syncthreads();
    int cur = 0;
    for (int ti = 0; ti < 5; ++ti) {
      const size_t row0 = (size_t)(t0 + ti) * 64;
      float4 ld[4];
      if (ti < 4) stage_issue(X, row0 + 64, ld, tid);
      f4acc aK[4] = {}, aV[4] = {}, aG[4] = {}, aB[4] = {};
#pragma unroll
      for (int ks = 0; ks < 4; ++ks) {
        const int ko = ks * 32 + kg;
        bfrag a0 = *reinterpret_cast<const bfrag*>(&Xs[cur][nl][ko]);
        bfrag a1 = *reinterpret_cast<const bfrag*>(&Xs[cur][16 + nl][ko]);
        bfrag a2 = *reinterpret_cast<const bfrag*>(&Xs[cur][32 + nl][ko]);
        bfrag a3 = *reinterpret_cast<const bfrag*>(&Xs[cur][48 + nl][ko]);
        aK[0] = MFMA16(a0, Bk[ks], aK[0]);
        aK[1] = MFMA16(a1, Bk[ks], aK[1]);
        aK[2] = MFMA16(a2, Bk[ks], aK[2]);
        aK[3] = MFMA16(a3, Bk[ks], aK[3]);
        aV[0] = MFMA16(a0, Bv[ks], aV[0]);
        aV[1] = MFMA16(a1, Bv[ks], aV[1]);
        aV[2] = MFMA16(a2, Bv[ks], aV[2]);
        aV[3] = MFMA16(a3, Bv[ks], aV[3]);
        aG[0] = MFMA16(a0, Bg[ks], aG[0]);
        aG[1] = MFMA16(a1, Bg[ks], aG[1]);
        aG[2] = MFMA16(a2, Bg[ks], aG[2]);
        aG[3] = MFMA16(a3, Bg[ks], aG[3]);
        if (w == 0) {
          aB[0] = MFMA16(a0, Bb[ks], aB[0]);
          aB[1] = MFMA16(a1, Bb[ks], aB[1]);
          aB[2] = MFMA16(a2, Bb[ks], aB[2]);
          aB[3] = MFMA16(a3, Bb[ks], aB[3]);
        }
      }
#pragma unroll
      for (int rf = 0; rf < 4; ++rf)
#pragma unroll
        for (int j = 0; j < 4; ++j) {
          int r = rf * 16 + r4 + j;
          float g = sigmoidf_fast(aG[rf][j] + gb);
          Stg[cur][r][slot] = (short)f2bf(aK[rf][j]);
          Stg[cur][r][slot + 2] = (short)f2bf(g * aV[rf][j]);
        }
      if (w == 0 && nl < 8) {
#pragma unroll
        for (int rf = 0; rf < 4; ++rf)
#pragma unroll
          for (int j = 0; j < 4; ++j)
            bsb[(row0 + rf * 16 + r4 + j) * 8 + nl] = (short)f2bf(aB[rf][j] * LOG2E);
      }
      if (ti > 0) {  // flush previous tile's KG — overlaps this tile
        const size_t rp = (size_t)(t0 + ti - 1) * 64;
        for (int u = tid; u < 2048; u += 512) {
          int r = u >> 5, o = (u & 31) * 8;
          *reinterpret_cast<bhalf8*>(KG + (rp + r) * KGROW + o) =
              *reinterpret_cast<const bhalf8*>(&Stg[cur ^ 1][r][o]);
        }
      }
      if (ti < 4) stage_write(Xs[cur ^ 1], ld, tid);
      __syncthreads();
      cur ^= 1;
    }
    {  // final flush: tile 4
      const size_t rp = (size_t)(t0 + 4) * 64;
      for (int u = tid; u < 2048; u += 512) {
        int r = u >> 5, o = (u & 31) * 8;
        *reinterpret_cast<bhalf8*>(KG + (rp + r) * KGROW + o) =
            *reinterpret_cast<const bhalf8*>(&Stg[cur ^ 1][r][o]);
      }
    }
  }
}

// ---------------- fused attention + output GEMM (256-thread blocks) ----------------
// 4 waves; block owns 32 targets; wave w handles targets w*8..w*8+7.
// Attention results -> bf16 LDS tile T[32][136]; barrier; waves 0..1 MFMA vs WoT.
__device__ __forceinline__ void mfma_pass(const short (*Xs)[136], int wave, int lane,
                                          const short* __restrict__ WT, f4acc acc[8]) {
  const int rl = wave * 16 + (lane & 15);
  const int kg = (lane >> 4) * 8;
  const int nl = lane & 15;
#pragma unroll
  for (int ks = 0; ks < 4; ++ks) {
    bfrag a = *reinterpret_cast<const bfrag*>(&Xs[rl][ks * 32 + kg]);
#pragma unroll
    for (int nf = 0; nf < 8; ++nf) {
      bfrag b = *reinterpret_cast<const bfrag*>(WT + (size_t)(nf * 16 + nl) * 128 + ks * 32 + kg);
      acc[nf] = MFMA16(a, b, acc[nf]);
    }
  }
}

__global__ __launch_bounds__(256) void k_attn(const uint2* __restrict__ Qp2,
                                              const uint4* __restrict__ KGp4,
                                              const short* __restrict__ bsb,
                                              const uint2* __restrict__ gtp2,
                                              const int* __restrict__ cntp,
                                              const ushort* __restrict__ elist,
                                              const short* __restrict__ WoT,
                                              float* __restrict__ out) {
  __shared__ short T[32][136];
  const int tid = threadIdx.x;
  const int w = tid >> 6;
  const int lane = tid & 63;
  const int p = lane & 31;
  const int h = p >> 2;
  const int hi = lane >> 5;
  const int tb = blockIdx.x * 32;  // 1250 * 32 == 40000 exact

  for (int tt = 0; tt < 8; ++tt) {
    const int t = tb + w * 8 + tt;
    uint2 qv = Qp2[(size_t)t * 32 + p];  // pre-scaled by 0.25*log2e
    float q0 = bflo(qv.x), q1 = bfhi(qv.x), q2 = bflo(qv.y), q3 = bfhi(qv.y);
    const int deg = min(cntp[t << 4], CAP);
    const int ebase = t * CAP;

    float ssum = 0.f, a0 = 0.f, a1 = 0.f, a2 = 0.f, a3 = 0.f;
    int i = 0;
    for (; i + 8 <= deg; i += 8) {
      int sv[4];
      uint4 kv[4];
      float bv[4], dd[4];
#pragma unroll
      for (int u = 0; u < 4; ++u) sv[u] = (int)elist[ebase + i + 2 * u + hi];
#pragma unroll
      for (int u = 0; u < 4; ++u) {
        kv[u] = KGp4[(size_t)sv[u] * 32 + p];
        bv[u] = bf2f(bsb[(size_t)sv[u] * 8 + h]);
      }
#pragma unroll
      for (int u = 0; u < 4; ++u)
        dd[u] = q0 * bflo(kv[u].x) + q1 * bfhi(kv[u].x) + q2 * bflo(kv[u].z) + q3 * bfhi(kv[u].z);
#pragma unroll
      for (int u = 0; u < 4; ++u) dd[u] += __shfl_xor(dd[u], 1);
#pragma unroll
      for (int u = 0; u < 4; ++u) dd[u] += __shfl_xor(dd[u], 2);
#pragma unroll
      for (int u = 0; u < 4; ++u) {
        float e = __builtin_amdgcn_exp2f(dd[u] + bv[u]);
        ssum += e;
        a0 = fmaf(e, bflo(kv[u].y), a0);
        a1 = fmaf(e, bfhi(kv[u].y), a1);
        a2 = fmaf(e, bflo(kv[u].w), a2);
        a3 = fmaf(e, bfhi(kv[u].w), a3);
      }
    }
    for (; i < deg; i += 2) {
      int idx = i + hi;
      float pen = 0.f;
      if (idx >= deg) { idx = deg - 1; pen = -1e30f; }  // odd tail: kill edge B
      int s = (int)elist[ebase + idx];
      uint4 kv = KGp4[(size_t)s * 32 + p];
      float bsv = bf2f(bsb[(size_t)s * 8 + h]);
      float d = q0 * bflo(kv.x) + q1 * bfhi(kv.x) + q2 * bflo(kv.z) + q3 * bfhi(kv.z);
      d += __shfl_xor(d, 1);
      d += __shfl_xor(d, 2);
      float e = __builtin_amdgcn_exp2f(d + bsv + pen);
      ssum += e;
      a0 = fmaf(e, bflo(kv.y), a0);
      a1 = fmaf(e, bfhi(kv.y), a1);
      a2 = fmaf(e, bflo(kv.w), a2);
      a3 = fmaf(e, bfhi(kv.w), a3);
    }
    ssum += __shfl_xor(ssum, 32);
    a0 += __shfl_xor(a0, 32);
    a1 += __shfl_xor(a1, 32);
    a2 += __shfl_xor(a2, 32);
    a3 += __shfl_xor(a3, 32);
    if (lane < 32) {
      float inv = 1.f / (ssum + 1e-12f);
      uint2 g2 = gtp2[(size_t)t * 32 + p];
      bhalf4 pk;
      pk[0] = (short)f2bf(bflo(g2.x) * a0 * inv);
      pk[1] = (short)f2bf(bfhi(g2.x) * a1 * inv);
      pk[2] = (short)f2bf(bflo(g2.y) * a2 * inv);
      pk[3] = (short)f2bf(bfhi(g2.y) * a3 * inv);
      *reinterpret_cast<bhalf4*>(&T[w * 8 + tt][p * 4]) = pk;
    }
  }
  __syncthreads();
  if (w < 2) {  // output GEMM: rows tb..tb+31 = T @ Wo
    f4acc acc[8] = {};
    mfma_pass(T, w, lane, WoT, acc);
    const int rbase = tb + w * 16 + ((lane >> 4) << 2);
    const int cl = lane & 15;
#pragma unroll
    for (int nf = 0; nf < 8; ++nf)
#pragma unroll
      for (int j = 0; j < 4; ++j)
        out[(size_t)(rbase + j) * 128 + nf * 16 + cl] = acc[nf][j];
  }
}

extern "C" void kernel_launch(void* const* d_in, const int* in_sizes, int n_in,
                              void* d_out, int out_size, void* d_ws, size_t ws_size,
                              hipStream_t stream) {
  const float* X_tgt = (const float*)d_in[0];
  const float* X_src = (const float*)d_in[1];
  const int* inc_tgt = (const int*)d_in[2];
  const int* inc_src = (const int*)d_in[3];
  const float* Wq    = (const float*)d_in[5];
  const float* Wkv   = (const float*)d_in[6];
  const float* Wbs   = (const float*)d_in[8];
  const float* Wgt_w = (const float*)d_in[9];
  const float* Wgt_b = (const float*)d_in[10];
  const float* Wgs_w = (const float*)d_in[11];
  const float* Wgs_b = (const float*)d_in[12];
  const float* Wo    = (const float*)d_in[13];
  float* out = (float*)d_out;

  char* ws = (char*)d_ws;
  short* Qb   = (short*)ws; ws += (size_t)NTGT * 128 * 2;
  short* KG   = (short*)ws; ws += (size_t)NSRC * KGROW * 2;
  short* gtb  = (short*)ws; ws += (size_t)NTGT * 128 * 2;
  short* bsb  = (short*)ws; ws += (size_t)NSRC * 8 * 2;
  int* cntp  = (int*)ws; ws += (size_t)NTGT * 16 * 4;  // 64B stride per counter
  ushort* elist = (ushort*)ws; ws += (size_t)NTGT * CAP * 2;
  short* WqT  = (short*)ws; ws += 128 * 128 * 2;
  short* WkT  = (short*)ws; ws += 128 * 128 * 2;
  short* WvT  = (short*)ws; ws += 128 * 128 * 2;
  short* WgtT = (short*)ws; ws += 128 * 128 * 2;
  short* WgsT = (short*)ws; ws += 128 * 128 * 2;
  short* WoT  = (short*)ws; ws += 128 * 128 * 2;
  short* WbsT = (short*)ws; ws += 16 * 128 * 2;

  k_prep<<<632, 256, 0, stream>>>(Wq, Wkv, Wgt_w, Wgs_w, Wo, Wbs, cntp,
                                  WqT, WkT, WvT, WgtT, WgsT, WoT, WbsT);
  k_fill<<<2560, 512, 0, stream>>>(inc_tgt, inc_src, cntp, elist);
  k_proj<<<250, 512, 0, stream>>>(X_tgt, X_src, WqT, WgtT, WkT, WvT, WgsT,
                                  WbsT, Wgt_b, Wgs_b, Qb, gtb, KG, bsb);
  k_attn<<<NTGT / 32, 256, 0, stream>>>((const uint2*)Qb, (const uint4*)KG, bsb,
                                        (const uint2*)gtb, cntp, elist, WoT, out);
}